// Round 3
// baseline (379.329 us; speedup 1.0000x reference)
//
#include <hip/hip_runtime.h>
#include <hip/hip_bf16.h>

typedef float f32x4 __attribute__((ext_vector_type(4)));
typedef __bf16 bf16x8 __attribute__((ext_vector_type(8)));

// ---------------------------------------------------------------------------
// async global -> LDS, 16B per lane (global_load_lds_dwordx4).
// LDS dest is wave-uniform base (+lane*16 by HW); pass per-lane ptr, compiler
// inserts readfirstlane. Global src IS per-lane.
// ---------------------------------------------------------------------------
__device__ __forceinline__ void gload16(const __bf16* g, __bf16* l) {
    __builtin_amdgcn_global_load_lds(
        (const __attribute__((address_space(1))) void*)g,
        (__attribute__((address_space(3))) void*)l,
        16, 0, 0);
}

// ---------------------------------------------------------------------------
// fp32 -> bf16 conversion, 8 elems / thread / iter (2x float4 load, 16B store)
// ---------------------------------------------------------------------------
__global__ __launch_bounds__(256) void cvt_bf16(const float* __restrict__ src,
                                                __bf16* __restrict__ dst,
                                                int n8) {
    int i = blockIdx.x * blockDim.x + threadIdx.x;
    int stride = gridDim.x * blockDim.x;
    const f32x4* s4 = (const f32x4*)src;
    bf16x8* d8 = (bf16x8*)dst;
    for (; i < n8; i += stride) {
        f32x4 a = s4[2 * i];
        f32x4 b = s4[2 * i + 1];
        bf16x8 o;
        o[0] = (__bf16)a[0]; o[1] = (__bf16)a[1];
        o[2] = (__bf16)a[2]; o[3] = (__bf16)a[3];
        o[4] = (__bf16)b[0]; o[5] = (__bf16)b[1];
        o[6] = (__bf16)b[2]; o[7] = (__bf16)b[3];
        d8[i] = o;
    }
}

// ---------------------------------------------------------------------------
// Fused gate+up GEMM: Hm[m,i] = silu(X@Wg^T) * (X@Wu^T), bf16 out.
// M=8192, N=I=4096, K=H=1024. 128x128 tile, BK=32, 4 waves (2x2), each wave
// 64x64 out = 4x4 frags of 16x16. Two accumulators share one A tile.
// ---------------------------------------------------------------------------
__global__ __launch_bounds__(256, 2) void ffn_gateup(
    const __bf16* __restrict__ X,   // [8192,1024]
    const __bf16* __restrict__ Wg,  // [4096,1024]
    const __bf16* __restrict__ Wu,  // [4096,1024]
    __bf16* __restrict__ Hm)        // [8192,4096]
{
    const int N = 4096, K = 1024;
    __shared__ __bf16 As[128 * 32];
    __shared__ __bf16 Gs[128 * 32];
    __shared__ __bf16 Us[128 * 32];

    const int t = threadIdx.x;
    const int lane = t & 63;
    const int w = t >> 6;
    const int wr = w >> 1, wc = w & 1;

    const int brow = blockIdx.y * 128;
    const int bcol = blockIdx.x * 128;

    // staging: thread t loads 16B at tile row t/4, col (t%4)*8 (rows 0..63),
    // second instruction covers rows 64..127. LDS layout linear row-major.
    const int srow = t >> 2;
    const int scol = (t & 3) << 3;

    const __bf16* gA = X + (size_t)(brow + srow) * K + scol;
    const __bf16* gG = Wg + (size_t)(bcol + srow) * K + scol;
    const __bf16* gU = Wu + (size_t)(bcol + srow) * K + scol;

    f32x4 accg[4][4] = {};
    f32x4 accu[4][4] = {};

    const int fr = lane & 15;   // row/col within 16
    const int kq = lane >> 4;   // k-quarter: k = kq*8 .. +7

    for (int k0 = 0; k0 < K; k0 += 32) {
        gload16(gA + k0,                    As + t * 8);
        gload16(gA + (size_t)64 * K + k0,   As + 2048 + t * 8);
        gload16(gG + k0,                    Gs + t * 8);
        gload16(gG + (size_t)64 * K + k0,   Gs + 2048 + t * 8);
        gload16(gU + k0,                    Us + t * 8);
        gload16(gU + (size_t)64 * K + k0,   Us + 2048 + t * 8);
        __syncthreads();   // compiler drains vmcnt before s_barrier

        bf16x8 a[4], bg[4], bu[4];
        #pragma unroll
        for (int m = 0; m < 4; ++m)
            a[m] = *(const bf16x8*)(As + (wr * 64 + m * 16 + fr) * 32 + kq * 8);
        #pragma unroll
        for (int n = 0; n < 4; ++n) {
            bg[n] = *(const bf16x8*)(Gs + (wc * 64 + n * 16 + fr) * 32 + kq * 8);
            bu[n] = *(const bf16x8*)(Us + (wc * 64 + n * 16 + fr) * 32 + kq * 8);
        }
        #pragma unroll
        for (int m = 0; m < 4; ++m) {
            #pragma unroll
            for (int n = 0; n < 4; ++n) {
                accg[m][n] = __builtin_amdgcn_mfma_f32_16x16x32_bf16(
                    a[m], bg[n], accg[m][n], 0, 0, 0);
                accu[m][n] = __builtin_amdgcn_mfma_f32_16x16x32_bf16(
                    a[m], bu[n], accu[m][n], 0, 0, 0);
            }
        }
        __syncthreads();
    }

    // epilogue: C/D layout col = lane&15, row = (lane>>4)*4 + j
    #pragma unroll
    for (int m = 0; m < 4; ++m) {
        #pragma unroll
        for (int n = 0; n < 4; ++n) {
            const int row0 = brow + wr * 64 + m * 16 + kq * 4;
            const int col  = bcol + wc * 64 + n * 16 + fr;
            #pragma unroll
            for (int j = 0; j < 4; ++j) {
                float g = accg[m][n][j];
                float u = accu[m][n][j];
                float h = (g / (1.0f + __expf(-g))) * u;   // silu(g)*u
                Hm[(size_t)(row0 + j) * N + col] = (__bf16)h;
            }
        }
    }
}

// ---------------------------------------------------------------------------
// Down GEMM: Y[m,h] = Hm @ Wd^T, fp32 out. M=8192, N=H=1024, K=I=4096.
// ---------------------------------------------------------------------------
__global__ __launch_bounds__(256, 2) void ffn_down(
    const __bf16* __restrict__ Hm,  // [8192,4096]
    const __bf16* __restrict__ Wd,  // [1024,4096]
    float* __restrict__ Y)          // [8192,1024]
{
    const int N = 1024, K = 4096;
    __shared__ __bf16 As[128 * 32];
    __shared__ __bf16 Bs[128 * 32];

    const int t = threadIdx.x;
    const int lane = t & 63;
    const int w = t >> 6;
    const int wr = w >> 1, wc = w & 1;

    const int brow = blockIdx.y * 128;
    const int bcol = blockIdx.x * 128;

    const int srow = t >> 2;
    const int scol = (t & 3) << 3;

    const __bf16* gA = Hm + (size_t)(brow + srow) * K + scol;
    const __bf16* gB = Wd + (size_t)(bcol + srow) * K + scol;

    f32x4 acc[4][4] = {};

    const int fr = lane & 15;
    const int kq = lane >> 4;

    for (int k0 = 0; k0 < K; k0 += 32) {
        gload16(gA + k0,                  As + t * 8);
        gload16(gA + (size_t)64 * K + k0, As + 2048 + t * 8);
        gload16(gB + k0,                  Bs + t * 8);
        gload16(gB + (size_t)64 * K + k0, Bs + 2048 + t * 8);
        __syncthreads();

        bf16x8 a[4], b[4];
        #pragma unroll
        for (int m = 0; m < 4; ++m)
            a[m] = *(const bf16x8*)(As + (wr * 64 + m * 16 + fr) * 32 + kq * 8);
        #pragma unroll
        for (int n = 0; n < 4; ++n)
            b[n] = *(const bf16x8*)(Bs + (wc * 64 + n * 16 + fr) * 32 + kq * 8);

        #pragma unroll
        for (int m = 0; m < 4; ++m) {
            #pragma unroll
            for (int n = 0; n < 4; ++n) {
                acc[m][n] = __builtin_amdgcn_mfma_f32_16x16x32_bf16(
                    a[m], b[n], acc[m][n], 0, 0, 0);
            }
        }
        __syncthreads();
    }

    #pragma unroll
    for (int m = 0; m < 4; ++m) {
        #pragma unroll
        for (int n = 0; n < 4; ++n) {
            const int row0 = brow + wr * 64 + m * 16 + kq * 4;
            const int col  = bcol + wc * 64 + n * 16 + fr;
            #pragma unroll
            for (int j = 0; j < 4; ++j) {
                Y[(size_t)(row0 + j) * N + col] = acc[m][n][j];
            }
        }
    }
}

// ---------------------------------------------------------------------------
extern "C" void kernel_launch(void* const* d_in, const int* in_sizes, int n_in,
                              void* d_out, int out_size, void* d_ws, size_t ws_size,
                              hipStream_t stream) {
    const float* x  = (const float*)d_in[0];
    const float* wg = (const float*)d_in[1];
    const float* wu = (const float*)d_in[2];
    const float* wd = (const float*)d_in[3];
    float* y = (float*)d_out;

    const size_t M = 8192, H = 1024, I = 4096;

    // ws layout (all bf16): Xb[M*H] Wgb[I*H] Wub[I*H] Wdb[H*I] Hm[M*I]
    __bf16* Xb  = (__bf16*)d_ws;
    __bf16* Wgb = Xb + M * H;
    __bf16* Wub = Wgb + I * H;
    __bf16* Wdb = Wub + I * H;
    __bf16* Hm  = Wdb + H * I;
    // needed: (M*H + 3*I*H + M*I)*2 bytes = 104 MiB

    cvt_bf16<<<1024, 256, 0, stream>>>(x,  Xb,  (int)(M * H / 8));
    cvt_bf16<<<512,  256, 0, stream>>>(wg, Wgb, (int)(I * H / 8));
    cvt_bf16<<<512,  256, 0, stream>>>(wu, Wub, (int)(I * H / 8));
    cvt_bf16<<<512,  256, 0, stream>>>(wd, Wdb, (int)(H * I / 8));

    ffn_gateup<<<dim3(I / 128, M / 128), 256, 0, stream>>>(Xb, Wgb, Wub, Hm);
    ffn_down  <<<dim3(H / 128, M / 128), 256, 0, stream>>>(Hm, Wdb, y);
}

// Round 4
// 347.018 us; speedup vs baseline: 1.0931x; 1.0931x over previous
//
#include <hip/hip_runtime.h>
#include <hip/hip_bf16.h>

typedef float f32x4 __attribute__((ext_vector_type(4)));
typedef __bf16 bf16x8 __attribute__((ext_vector_type(8)));

// ---------------------------------------------------------------------------
// async global -> LDS, 16B/lane. LDS dest must be linear (wave base + lane*16).
// ---------------------------------------------------------------------------
__device__ __forceinline__ void gload16(const __bf16* g, __bf16* l) {
    __builtin_amdgcn_global_load_lds(
        (const __attribute__((address_space(1))) void*)g,
        (__attribute__((address_space(3))) void*)l, 16, 0, 0);
}

// st_16x32 swizzled LDS fragment read: logical (row, kbyte) in a [rows][64]bf16
// tile -> physical = L ^ ((L>>9)&1)<<5  (involution; bit5 < bit9, no feedback)
__device__ __forceinline__ bf16x8 frag(const __bf16* buf, int row, int kb) {
    int L = (row << 7) + kb;
    int P = L ^ (((L >> 9) & 1) << 5);
    return *(const bf16x8*)((const char*)buf + P);
}

// stage one 8KB chunk (64 rows x 64 cols bf16): linear LDS dest, the global
// SOURCE is inverse-swizzled so that swizzled ds_reads see logical data.
#define STG(SRC, C, T, NTT, KK, DSTB)                                         \
    if ((T) < (NTT))                                                          \
        gload16((SRC) + (size_t)(C) * 64 * (KK) + (size_t)(T) * 64,           \
                (DSTB) + (C) * 4096 + t5 * 8)

#define LDA4(BUF, MO)                                                         \
    _Pragma("unroll") for (int m_ = 0; m_ < 4; ++m_) {                        \
        a[m_][0] = frag(BUF, wr * 128 + (m_ + MO) * 16 + fr, kq * 16);        \
        a[m_][1] = frag(BUF, wr * 128 + (m_ + MO) * 16 + fr, 64 + kq * 16);   \
    }

#define LDB2(DST, BUF)                                                        \
    _Pragma("unroll") for (int n_ = 0; n_ < 2; ++n_) {                        \
        DST[n_][0] = frag(BUF, wc * 32 + n_ * 16 + fr, kq * 16);              \
        DST[n_][1] = frag(BUF, wc * 32 + n_ * 16 + fr, 64 + kq * 16);         \
    }

#define MFMA16(ACC, BF, MO)                                                   \
    __builtin_amdgcn_s_setprio(1);                                            \
    _Pragma("unroll") for (int m_ = 0; m_ < 4; ++m_) {                        \
        _Pragma("unroll") for (int n_ = 0; n_ < 2; ++n_) {                    \
            ACC[m_ + MO][n_] = __builtin_amdgcn_mfma_f32_16x16x32_bf16(       \
                a[m_][0], BF[n_][0], ACC[m_ + MO][n_], 0, 0, 0);              \
            ACC[m_ + MO][n_] = __builtin_amdgcn_mfma_f32_16x16x32_bf16(       \
                a[m_][1], BF[n_][1], ACC[m_ + MO][n_], 0, 0, 0);              \
        }                                                                     \
    }                                                                         \
    __builtin_amdgcn_s_setprio(0);

#define BAR() __builtin_amdgcn_s_barrier()
#define WAITV(N) asm volatile("s_waitcnt vmcnt(" #N ")" ::: "memory")

// ---------------------------------------------------------------------------
// fp32 -> bf16 conversion, 8 elems/thread/iter
// ---------------------------------------------------------------------------
__global__ __launch_bounds__(256) void cvt_bf16(const float* __restrict__ src,
                                                __bf16* __restrict__ dst,
                                                int n8) {
    int i = blockIdx.x * blockDim.x + threadIdx.x;
    int stride = gridDim.x * blockDim.x;
    const f32x4* s4 = (const f32x4*)src;
    bf16x8* d8 = (bf16x8*)dst;
    for (; i < n8; i += stride) {
        f32x4 va = s4[2 * i];
        f32x4 vb = s4[2 * i + 1];
        bf16x8 o;
        o[0] = (__bf16)va[0]; o[1] = (__bf16)va[1];
        o[2] = (__bf16)va[2]; o[3] = (__bf16)va[3];
        o[4] = (__bf16)vb[0]; o[5] = (__bf16)vb[1];
        o[6] = (__bf16)vb[2]; o[7] = (__bf16)vb[3];
        d8[i] = o;
    }
}

// ---------------------------------------------------------------------------
// Gate+Up GEMM, 8-phase schedule. M=8192, N=4096, K=1024.
// BM=256, BN=128, BK=64. 8 waves (2Mx4N), per-wave out 128x32 per matrix.
// Phases per K-tile: p0=(gate,mh0,12 ds) p1=(up,mh0,4 ds) p2=(gate,mh1,8 ds)
// p3=(up,mh1,0 ds). 2 stage-loads/phase, vmcnt(6) once per K-tile.
// ---------------------------------------------------------------------------
__global__ __launch_bounds__(512, 2) void ffn_gateup(
    const __bf16* __restrict__ X,   // [8192,1024]
    const __bf16* __restrict__ Wg,  // [4096,1024]
    const __bf16* __restrict__ Wu,  // [4096,1024]
    __bf16* __restrict__ Hm)        // [8192,4096]
{
    constexpr int K = 1024, NT = 16;
    __shared__ __bf16 lds[65536];          // 128 KiB
    __bf16* const A0p = lds;               // 32KB per A buf
    __bf16* const A1p = lds + 16384;
    __bf16* const G0p = lds + 32768;       // 16KB per G buf
    __bf16* const G1p = lds + 40960;
    __bf16* const U0p = lds + 49152;
    __bf16* const U1p = lds + 57344;

    const int t5 = threadIdx.x;
    const int lane = t5 & 63, w = t5 >> 6;
    const int wr = w >> 2, wc = w & 3;
    const int fr = lane & 15, kq = lane >> 4;

    const int brow = blockIdx.y * 256;
    const int bcol = blockIdx.x * 128;

    const int srow = t5 >> 3;
    const int scol = ((t5 & 7) << 3) ^ (((t5 >> 5) & 1) << 4);  // inv-swizzle

    const __bf16* Xs = X  + (size_t)(brow + srow) * K + scol;
    const __bf16* Gg = Wg + (size_t)(bcol + srow) * K + scol;
    const __bf16* Uu = Wu + (size_t)(bcol + srow) * K + scol;

    f32x4 accg[8][2] = {}, accu[8][2] = {};
    bf16x8 a[4][2], g[2][2], u[2][2];

    // prologue: tile0 full (8 loads), tile1 A02+G+U (6 loads)
    STG(Xs, 0, 0, NT, K, A0p); STG(Xs, 2, 0, NT, K, A0p);
    STG(Gg, 0, 0, NT, K, G0p); STG(Gg, 1, 0, NT, K, G0p);
    STG(Uu, 0, 0, NT, K, U0p); STG(Uu, 1, 0, NT, K, U0p);
    STG(Xs, 1, 0, NT, K, A0p); STG(Xs, 3, 0, NT, K, A0p);
    STG(Xs, 0, 1, NT, K, A1p); STG(Xs, 2, 1, NT, K, A1p);
    STG(Gg, 0, 1, NT, K, G1p); STG(Gg, 1, 1, NT, K, G1p);
    STG(Uu, 0, 1, NT, K, U1p); STG(Uu, 1, 1, NT, K, U1p);
    WAITV(6);
    BAR();

    for (int t = 0; t < NT; t += 2) {
        // ---- p0: tile t, gate, mh0 ----
        LDA4(A0p, 0);
        LDB2(g, G0p);
        STG(Xs, 1, t + 1, NT, K, A1p); STG(Xs, 3, t + 1, NT, K, A1p);
        BAR();
        MFMA16(accg, g, 0);
        BAR();
        // ---- p1: tile t, up, mh0 ----
        LDB2(u, U0p);
        STG(Xs, 0, t + 2, NT, K, A0p); STG(Xs, 2, t + 2, NT, K, A0p);
        BAR();
        MFMA16(accu, u, 0);
        BAR();
        // ---- p2: tile t, gate, mh1 ----
        LDA4(A0p, 4);
        STG(Gg, 0, t + 2, NT, K, G0p); STG(Gg, 1, t + 2, NT, K, G0p);
        BAR();
        MFMA16(accg, g, 4);
        BAR();
        // ---- p3: tile t, up, mh1 ----
        STG(Uu, 0, t + 2, NT, K, U0p); STG(Uu, 1, t + 2, NT, K, U0p);
        BAR();
        MFMA16(accu, u, 4);
        if (t + 2 < NT) { WAITV(6); } else { WAITV(0); }
        BAR();
        // ---- p4: tile t+1, gate, mh0 ----
        LDA4(A1p, 0);
        LDB2(g, G1p);
        STG(Xs, 1, t + 2, NT, K, A0p); STG(Xs, 3, t + 2, NT, K, A0p);
        BAR();
        MFMA16(accg, g, 0);
        BAR();
        // ---- p5: tile t+1, up, mh0 ----
        LDB2(u, U1p);
        STG(Xs, 0, t + 3, NT, K, A1p); STG(Xs, 2, t + 3, NT, K, A1p);
        BAR();
        MFMA16(accu, u, 0);
        BAR();
        // ---- p6: tile t+1, gate, mh1 ----
        LDA4(A1p, 4);
        STG(Gg, 0, t + 3, NT, K, G1p); STG(Gg, 1, t + 3, NT, K, G1p);
        BAR();
        MFMA16(accg, g, 4);
        BAR();
        // ---- p7: tile t+1, up, mh1 ----
        STG(Uu, 0, t + 3, NT, K, U1p); STG(Uu, 1, t + 3, NT, K, U1p);
        BAR();
        MFMA16(accu, u, 4);
        if (t + 3 < NT) { WAITV(6); } else { WAITV(0); }
        BAR();
    }

    // epilogue: C/D layout col = lane&15, row = (lane>>4)*4 + j
    #pragma unroll
    for (int m = 0; m < 8; ++m) {
        #pragma unroll
        for (int n = 0; n < 2; ++n) {
            const int row0 = brow + wr * 128 + m * 16 + kq * 4;
            const int col  = bcol + wc * 32 + n * 16 + fr;
            #pragma unroll
            for (int j = 0; j < 4; ++j) {
                float gg = accg[m][n][j];
                float uu = accu[m][n][j];
                float h = (gg / (1.0f + __expf(-gg))) * uu;
                Hm[(size_t)(row0 + j) * 4096 + col] = (__bf16)h;
            }
        }
    }
}

// ---------------------------------------------------------------------------
// Down GEMM, 4-phase schedule. M=8192, N=1024, K=4096.
// BM=256, BN=128, BK=64. Phases per K-tile: p0=(mh0,12 ds) p1=(mh1,8 ds).
// 3 stage-loads/phase, vmcnt(3) once per K-tile.
// ---------------------------------------------------------------------------
__global__ __launch_bounds__(512, 2) void ffn_down(
    const __bf16* __restrict__ Hm,  // [8192,4096]
    const __bf16* __restrict__ Wd,  // [1024,4096]
    float* __restrict__ Y)          // [8192,1024]
{
    constexpr int K = 4096, NT = 64;
    __shared__ __bf16 lds[49152];          // 96 KiB
    __bf16* const A0p = lds;
    __bf16* const A1p = lds + 16384;
    __bf16* const B0p = lds + 32768;
    __bf16* const B1p = lds + 40960;

    const int t5 = threadIdx.x;
    const int lane = t5 & 63, w = t5 >> 6;
    const int wr = w >> 2, wc = w & 3;
    const int fr = lane & 15, kq = lane >> 4;

    const int brow = blockIdx.y * 256;
    const int bcol = blockIdx.x * 128;

    const int srow = t5 >> 3;
    const int scol = ((t5 & 7) << 3) ^ (((t5 >> 5) & 1) << 4);

    const __bf16* Hs = Hm + (size_t)(brow + srow) * K + scol;
    const __bf16* Ws = Wd + (size_t)(bcol + srow) * K + scol;

    f32x4 acc[8][2] = {};
    bf16x8 a[4][2], b[2][2];

    // prologue: tile0 full (6 loads), tile1 A02+Bc0 (3 loads)
    STG(Hs, 0, 0, NT, K, A0p); STG(Hs, 2, 0, NT, K, A0p);
    STG(Ws, 0, 0, NT, K, B0p); STG(Ws, 1, 0, NT, K, B0p);
    STG(Hs, 1, 0, NT, K, A0p); STG(Hs, 3, 0, NT, K, A0p);
    STG(Hs, 0, 1, NT, K, A1p); STG(Hs, 2, 1, NT, K, A1p);
    STG(Ws, 0, 1, NT, K, B1p);
    WAITV(3);
    BAR();

    for (int t = 0; t < NT; t += 2) {
        // ---- p0: tile t, mh0 ----
        LDA4(A0p, 0);
        LDB2(b, B0p);
        STG(Ws, 1, t + 1, NT, K, B1p);
        STG(Hs, 1, t + 1, NT, K, A1p); STG(Hs, 3, t + 1, NT, K, A1p);
        BAR();
        MFMA16(acc, b, 0);
        BAR();
        // ---- p1: tile t, mh1 ----
        LDA4(A0p, 4);
        STG(Hs, 0, t + 2, NT, K, A0p); STG(Hs, 2, t + 2, NT, K, A0p);
        STG(Ws, 0, t + 2, NT, K, B0p);
        BAR();
        MFMA16(acc, b, 4);
        if (t + 2 < NT) { WAITV(3); } else { WAITV(0); }
        BAR();
        // ---- p2: tile t+1, mh0 ----
        LDA4(A1p, 0);
        LDB2(b, B1p);
        STG(Ws, 1, t + 2, NT, K, B0p);
        STG(Hs, 1, t + 2, NT, K, A0p); STG(Hs, 3, t + 2, NT, K, A0p);
        BAR();
        MFMA16(acc, b, 0);
        BAR();
        // ---- p3: tile t+1, mh1 ----
        LDA4(A1p, 4);
        STG(Hs, 0, t + 3, NT, K, A1p); STG(Hs, 2, t + 3, NT, K, A1p);
        STG(Ws, 0, t + 3, NT, K, B1p);
        BAR();
        MFMA16(acc, b, 4);
        if (t + 3 < NT) { WAITV(3); } else { WAITV(0); }
        BAR();
    }

    #pragma unroll
    for (int m = 0; m < 8; ++m) {
        #pragma unroll
        for (int n = 0; n < 2; ++n) {
            const int row0 = brow + wr * 128 + m * 16 + kq * 4;
            const int col  = bcol + wc * 32 + n * 16 + fr;
            #pragma unroll
            for (int j = 0; j < 4; ++j) {
                Y[(size_t)(row0 + j) * 1024 + col] = acc[m][n][j];
            }
        }
    }
}

// ---------------------------------------------------------------------------
extern "C" void kernel_launch(void* const* d_in, const int* in_sizes, int n_in,
                              void* d_out, int out_size, void* d_ws, size_t ws_size,
                              hipStream_t stream) {
    const float* x  = (const float*)d_in[0];
    const float* wg = (const float*)d_in[1];
    const float* wu = (const float*)d_in[2];
    const float* wd = (const float*)d_in[3];
    float* y = (float*)d_out;

    const size_t M = 8192, H = 1024, I = 4096;

    __bf16* Xb  = (__bf16*)d_ws;
    __bf16* Wgb = Xb + M * H;
    __bf16* Wub = Wgb + I * H;
    __bf16* Wdb = Wub + I * H;
    __bf16* Hm  = Wdb + H * I;
    // needed: (M*H + 3*I*H + M*I)*2 bytes = 104 MiB

    cvt_bf16<<<1024, 256, 0, stream>>>(x,  Xb,  (int)(M * H / 8));
    cvt_bf16<<<512,  256, 0, stream>>>(wg, Wgb, (int)(I * H / 8));
    cvt_bf16<<<512,  256, 0, stream>>>(wu, Wub, (int)(I * H / 8));
    cvt_bf16<<<512,  256, 0, stream>>>(wd, Wdb, (int)(H * I / 8));

    ffn_gateup<<<dim3(I / 128, M / 256), 512, 0, stream>>>(Xb, Wgb, Wub, Hm);
    ffn_down  <<<dim3(H / 128, M / 256), 512, 0, stream>>>(Hm, Wdb, y);
}

// Round 5
// 335.715 us; speedup vs baseline: 1.1299x; 1.0337x over previous
//
#include <hip/hip_runtime.h>
#include <hip/hip_bf16.h>

typedef float f32x4 __attribute__((ext_vector_type(4)));
typedef __bf16 bf16x8 __attribute__((ext_vector_type(8)));

// ---------------------------------------------------------------------------
// async global -> LDS, 16B/lane. LDS dest must be linear (wave base + lane*16).
// ---------------------------------------------------------------------------
__device__ __forceinline__ void gload16(const __bf16* g, __bf16* l) {
    __builtin_amdgcn_global_load_lds(
        (const __attribute__((address_space(1))) void*)g,
        (__attribute__((address_space(3))) void*)l, 16, 0, 0);
}

// Swizzled LDS fragment read. Logical tile [rows][64]bf16, row stride 128B.
// Physical byte = row*128 + (kb ^ ((row&7)<<4)): XOR row bits[2:0] into the
// 16B-slot index (byte bits[6:4]). 8 consecutive rows -> 8 distinct 16B slots
// -> conflict-free ds_read_b128 (2-lane aliasing is free). Involution.
__device__ __forceinline__ bf16x8 frag(const __bf16* buf, int row, int kb) {
    int P = (row << 7) + (kb ^ ((row & 7) << 4));
    return *(const bf16x8*)((const char*)buf + P);
}

// stage one 8KB chunk (64 rows x 64 cols bf16): linear LDS dest; global SOURCE
// is inverse-swizzled (same involution) so swizzled ds_reads see logical data.
#define STG(SRC, C, T, NTT, KK, DSTB)                                         \
    if ((T) < (NTT))                                                          \
        gload16((SRC) + (size_t)(C) * 64 * (KK) + (size_t)(T) * 64,           \
                (DSTB) + (C) * 4096 + t5 * 8)

#define LDA4(BUF, MO)                                                         \
    _Pragma("unroll") for (int m_ = 0; m_ < 4; ++m_) {                        \
        a[m_][0] = frag(BUF, wr * 128 + (m_ + MO) * 16 + fr, kq * 16);        \
        a[m_][1] = frag(BUF, wr * 128 + (m_ + MO) * 16 + fr, 64 + kq * 16);   \
    }

#define LDB2(DST, BUF)                                                        \
    _Pragma("unroll") for (int n_ = 0; n_ < 2; ++n_) {                        \
        DST[n_][0] = frag(BUF, wc * 32 + n_ * 16 + fr, kq * 16);              \
        DST[n_][1] = frag(BUF, wc * 32 + n_ * 16 + fr, 64 + kq * 16);         \
    }

#define MFMA16(ACC, BF, MO)                                                   \
    __builtin_amdgcn_s_setprio(1);                                            \
    _Pragma("unroll") for (int m_ = 0; m_ < 4; ++m_) {                        \
        _Pragma("unroll") for (int n_ = 0; n_ < 2; ++n_) {                    \
            ACC[m_ + MO][n_] = __builtin_amdgcn_mfma_f32_16x16x32_bf16(       \
                a[m_][0], BF[n_][0], ACC[m_ + MO][n_], 0, 0, 0);              \
            ACC[m_ + MO][n_] = __builtin_amdgcn_mfma_f32_16x16x32_bf16(       \
                a[m_][1], BF[n_][1], ACC[m_ + MO][n_], 0, 0, 0);              \
        }                                                                     \
    }                                                                         \
    __builtin_amdgcn_s_setprio(0);

#define BAR() __builtin_amdgcn_s_barrier()
#define WAITV(N) asm volatile("s_waitcnt vmcnt(" #N ")" ::: "memory")

// ---------------------------------------------------------------------------
// fp32 -> bf16 conversion, 8 elems/thread/iter
// ---------------------------------------------------------------------------
__global__ __launch_bounds__(256) void cvt_bf16(const float* __restrict__ src,
                                                __bf16* __restrict__ dst,
                                                int n8) {
    int i = blockIdx.x * blockDim.x + threadIdx.x;
    int stride = gridDim.x * blockDim.x;
    const f32x4* s4 = (const f32x4*)src;
    bf16x8* d8 = (bf16x8*)dst;
    for (; i < n8; i += stride) {
        f32x4 va = s4[2 * i];
        f32x4 vb = s4[2 * i + 1];
        bf16x8 o;
        o[0] = (__bf16)va[0]; o[1] = (__bf16)va[1];
        o[2] = (__bf16)va[2]; o[3] = (__bf16)va[3];
        o[4] = (__bf16)vb[0]; o[5] = (__bf16)vb[1];
        o[6] = (__bf16)vb[2]; o[7] = (__bf16)vb[3];
        d8[i] = o;
    }
}

// ---------------------------------------------------------------------------
// Gate+Up GEMM, 8-phase schedule. M=8192, N=4096, K=1024.
// BM=256, BN=128, BK=64. 8 waves (2Mx4N), per-wave out 128x32 per matrix.
// Chunk ledger: mh0 reads chunks {0,2}, mh1 reads {1,3} of A; B reads {0,1}.
// 2 stage-loads/phase, vmcnt(6) once per K-tile (3 half-sets in flight).
// ---------------------------------------------------------------------------
__global__ __launch_bounds__(512, 2) void ffn_gateup(
    const __bf16* __restrict__ X,   // [8192,1024]
    const __bf16* __restrict__ Wg,  // [4096,1024]
    const __bf16* __restrict__ Wu,  // [4096,1024]
    __bf16* __restrict__ Hm)        // [8192,4096]
{
    constexpr int K = 1024, NT = 16;
    __shared__ __bf16 lds[65536];          // 128 KiB
    __bf16* const A0p = lds;               // 32KB per A buf
    __bf16* const A1p = lds + 16384;
    __bf16* const G0p = lds + 32768;       // 16KB per G buf
    __bf16* const G1p = lds + 40960;
    __bf16* const U0p = lds + 49152;
    __bf16* const U1p = lds + 57344;

    const int t5 = threadIdx.x;
    const int lane = t5 & 63, w = t5 >> 6;
    const int wr = w >> 2, wc = w & 3;
    const int fr = lane & 15, kq = lane >> 4;

    const int brow = blockIdx.y * 256;
    const int bcol = blockIdx.x * 128;

    const int srow = t5 >> 3;
    // inverse of frag()'s swizzle: thread t writes physical slot t&7 in
    // physical row t>>3 -> must fetch logical col-slot (t&7)^(row&7).
    const int scol = (((t5 & 7) ^ ((t5 >> 3) & 7)) << 3);

    const __bf16* Xs = X  + (size_t)(brow + srow) * K + scol;
    const __bf16* Gg = Wg + (size_t)(bcol + srow) * K + scol;
    const __bf16* Uu = Wu + (size_t)(bcol + srow) * K + scol;

    f32x4 accg[8][2] = {}, accu[8][2] = {};
    bf16x8 a[4][2], g[2][2], u[2][2];

    // prologue: tile0 full (8 loads), tile1 A02+G+U (6 loads)
    STG(Xs, 0, 0, NT, K, A0p); STG(Xs, 2, 0, NT, K, A0p);
    STG(Gg, 0, 0, NT, K, G0p); STG(Gg, 1, 0, NT, K, G0p);
    STG(Uu, 0, 0, NT, K, U0p); STG(Uu, 1, 0, NT, K, U0p);
    STG(Xs, 1, 0, NT, K, A0p); STG(Xs, 3, 0, NT, K, A0p);
    STG(Xs, 0, 1, NT, K, A1p); STG(Xs, 2, 1, NT, K, A1p);
    STG(Gg, 0, 1, NT, K, G1p); STG(Gg, 1, 1, NT, K, G1p);
    STG(Uu, 0, 1, NT, K, U1p); STG(Uu, 1, 1, NT, K, U1p);
    WAITV(6);
    BAR();

    for (int t = 0; t < NT; t += 2) {
        // ---- p0: tile t, gate, mh0 ----
        LDA4(A0p, 0);
        LDB2(g, G0p);
        STG(Xs, 1, t + 1, NT, K, A1p); STG(Xs, 3, t + 1, NT, K, A1p);
        BAR();
        MFMA16(accg, g, 0);
        BAR();
        // ---- p1: tile t, up, mh0 ----
        LDB2(u, U0p);
        STG(Xs, 0, t + 2, NT, K, A0p); STG(Xs, 2, t + 2, NT, K, A0p);
        BAR();
        MFMA16(accu, u, 0);
        BAR();
        // ---- p2: tile t, gate, mh1 ----
        LDA4(A0p, 4);
        STG(Gg, 0, t + 2, NT, K, G0p); STG(Gg, 1, t + 2, NT, K, G0p);
        BAR();
        MFMA16(accg, g, 4);
        BAR();
        // ---- p3: tile t, up, mh1 ----
        STG(Uu, 0, t + 2, NT, K, U0p); STG(Uu, 1, t + 2, NT, K, U0p);
        BAR();
        MFMA16(accu, u, 4);
        if (t + 2 < NT) { WAITV(6); } else { WAITV(0); }
        BAR();
        // ---- p4: tile t+1, gate, mh0 ----
        LDA4(A1p, 0);
        LDB2(g, G1p);
        STG(Xs, 1, t + 2, NT, K, A0p); STG(Xs, 3, t + 2, NT, K, A0p);
        BAR();
        MFMA16(accg, g, 0);
        BAR();
        // ---- p5: tile t+1, up, mh0 ----
        LDB2(u, U1p);
        STG(Xs, 0, t + 3, NT, K, A1p); STG(Xs, 2, t + 3, NT, K, A1p);
        BAR();
        MFMA16(accu, u, 0);
        BAR();
        // ---- p6: tile t+1, gate, mh1 ----
        LDA4(A1p, 4);
        STG(Gg, 0, t + 3, NT, K, G1p); STG(Gg, 1, t + 3, NT, K, G1p);
        BAR();
        MFMA16(accg, g, 4);
        BAR();
        // ---- p7: tile t+1, up, mh1 ----
        STG(Uu, 0, t + 3, NT, K, U1p); STG(Uu, 1, t + 3, NT, K, U1p);
        BAR();
        MFMA16(accu, u, 4);
        if (t + 3 < NT) { WAITV(6); } else { WAITV(0); }
        BAR();
    }

    // epilogue: C/D layout col = lane&15, row = (lane>>4)*4 + j
    #pragma unroll
    for (int m = 0; m < 8; ++m) {
        #pragma unroll
        for (int n = 0; n < 2; ++n) {
            const int row0 = brow + wr * 128 + m * 16 + kq * 4;
            const int col  = bcol + wc * 32 + n * 16 + fr;
            #pragma unroll
            for (int j = 0; j < 4; ++j) {
                float gg = accg[m][n][j];
                float uu = accu[m][n][j];
                float h = (gg / (1.0f + __expf(-gg))) * uu;
                Hm[(size_t)(row0 + j) * 4096 + col] = (__bf16)h;
            }
        }
    }
}

// ---------------------------------------------------------------------------
// Down GEMM, 4-phase schedule. M=8192, N=1024, K=4096.
// BM=256, BN=128, BK=64. 3 stage-loads/phase, vmcnt(3) once per K-tile.
// ---------------------------------------------------------------------------
__global__ __launch_bounds__(512, 2) void ffn_down(
    const __bf16* __restrict__ Hm,  // [8192,4096]
    const __bf16* __restrict__ Wd,  // [1024,4096]
    float* __restrict__ Y)          // [8192,1024]
{
    constexpr int K = 4096, NT = 64;
    __shared__ __bf16 lds[49152];          // 96 KiB
    __bf16* const A0p = lds;
    __bf16* const A1p = lds + 16384;
    __bf16* const B0p = lds + 32768;
    __bf16* const B1p = lds + 40960;

    const int t5 = threadIdx.x;
    const int lane = t5 & 63, w = t5 >> 6;
    const int wr = w >> 2, wc = w & 3;
    const int fr = lane & 15, kq = lane >> 4;

    const int brow = blockIdx.y * 256;
    const int bcol = blockIdx.x * 128;

    const int srow = t5 >> 3;
    const int scol = (((t5 & 7) ^ ((t5 >> 3) & 7)) << 3);

    const __bf16* Hs = Hm + (size_t)(brow + srow) * K + scol;
    const __bf16* Ws = Wd + (size_t)(bcol + srow) * K + scol;

    f32x4 acc[8][2] = {};
    bf16x8 a[4][2], b[2][2];

    // prologue: tile0 full (6 loads), tile1 A02+Bc0 (3 loads)
    STG(Hs, 0, 0, NT, K, A0p); STG(Hs, 2, 0, NT, K, A0p);
    STG(Ws, 0, 0, NT, K, B0p); STG(Ws, 1, 0, NT, K, B0p);
    STG(Hs, 1, 0, NT, K, A0p); STG(Hs, 3, 0, NT, K, A0p);
    STG(Hs, 0, 1, NT, K, A1p); STG(Hs, 2, 1, NT, K, A1p);
    STG(Ws, 0, 1, NT, K, B1p);
    WAITV(3);
    BAR();

    for (int t = 0; t < NT; t += 2) {
        // ---- p0: tile t, mh0 ----
        LDA4(A0p, 0);
        LDB2(b, B0p);
        STG(Ws, 1, t + 1, NT, K, B1p);
        STG(Hs, 1, t + 1, NT, K, A1p); STG(Hs, 3, t + 1, NT, K, A1p);
        BAR();
        MFMA16(acc, b, 0);
        BAR();
        // ---- p1: tile t, mh1 ----
        LDA4(A0p, 4);
        STG(Hs, 0, t + 2, NT, K, A0p); STG(Hs, 2, t + 2, NT, K, A0p);
        STG(Ws, 0, t + 2, NT, K, B0p);
        BAR();
        MFMA16(acc, b, 4);
        if (t + 2 < NT) { WAITV(3); } else { WAITV(0); }
        BAR();
        // ---- p2: tile t+1, mh0 ----
        LDA4(A1p, 0);
        LDB2(b, B1p);
        STG(Ws, 1, t + 2, NT, K, B0p);
        STG(Hs, 1, t + 2, NT, K, A0p); STG(Hs, 3, t + 2, NT, K, A0p);
        BAR();
        MFMA16(acc, b, 0);
        BAR();
        // ---- p3: tile t+1, mh1 ----
        LDA4(A1p, 4);
        STG(Hs, 0, t + 3, NT, K, A1p); STG(Hs, 2, t + 3, NT, K, A1p);
        STG(Ws, 0, t + 3, NT, K, B1p);
        BAR();
        MFMA16(acc, b, 4);
        if (t + 3 < NT) { WAITV(3); } else { WAITV(0); }
        BAR();
    }

    #pragma unroll
    for (int m = 0; m < 8; ++m) {
        #pragma unroll
        for (int n = 0; n < 2; ++n) {
            const int row0 = brow + wr * 128 + m * 16 + kq * 4;
            const int col  = bcol + wc * 32 + n * 16 + fr;
            #pragma unroll
            for (int j = 0; j < 4; ++j) {
                Y[(size_t)(row0 + j) * 1024 + col] = acc[m][n][j];
            }
        }
    }
}

// ---------------------------------------------------------------------------
extern "C" void kernel_launch(void* const* d_in, const int* in_sizes, int n_in,
                              void* d_out, int out_size, void* d_ws, size_t ws_size,
                              hipStream_t stream) {
    const float* x  = (const float*)d_in[0];
    const float* wg = (const float*)d_in[1];
    const float* wu = (const float*)d_in[2];
    const float* wd = (const float*)d_in[3];
    float* y = (float*)d_out;

    const size_t M = 8192, H = 1024, I = 4096;

    __bf16* Xb  = (__bf16*)d_ws;
    __bf16* Wgb = Xb + M * H;
    __bf16* Wub = Wgb + I * H;
    __bf16* Wdb = Wub + I * H;
    __bf16* Hm  = Wdb + H * I;
    // needed: (M*H + 3*I*H + M*I)*2 bytes = 104 MiB

    cvt_bf16<<<1024, 256, 0, stream>>>(x,  Xb,  (int)(M * H / 8));
    cvt_bf16<<<512,  256, 0, stream>>>(wg, Wgb, (int)(I * H / 8));
    cvt_bf16<<<512,  256, 0, stream>>>(wu, Wub, (int)(I * H / 8));
    cvt_bf16<<<512,  256, 0, stream>>>(wd, Wdb, (int)(H * I / 8));

    ffn_gateup<<<dim3(I / 128, M / 256), 512, 0, stream>>>(Xb, Wgb, Wub, Hm);
    ffn_down  <<<dim3(H / 128, M / 256), 512, 0, stream>>>(Hm, Wdb, y);
}